// Round 7
// baseline (193.811 us; speedup 1.0000x reference)
//
#include <hip/hip_runtime.h>
#include <hip/hip_bf16.h>

// Sparse encoder layer: 3x submanifold conv (27-pt) + strided conv (8-pt),
// 4x training-mode BN+ReLU. bf16 MFMA (fp32 accum) for all convs.
//
// R6 finding: VGPR=44 proves the compiler serialized the "burst" gathers
// (needs ~70 live); fused BN added 27x-redundant VALU on the critical chain.
// R7: un-fuse BN (separate streaming pass), force the 14-gather burst live
// across a sched_barrier(0). Keep perm-space spatial re-indexing (L2 hits).
//
// ws layout (bytes):
//   [0, 32768)          : stats partials, 4 stages x NCOPY(32) x 64 floats
//   [32768, 215040)     : W1t/W2at/W2bt bf16 [27][32][32] + W3t [8][32][32]
//   [215040, +3x8.4MB)  : X, T, FB bf16 [N,32]  (perm space)
//   then: perm[N], invperm[N], nbrP[N*27], childP[M*8], blockCnt[256]

typedef __bf16 bf16_8 __attribute__((ext_vector_type(8)));
typedef float  f32x4  __attribute__((ext_vector_type(4)));

#define EPSV 1e-5f
#define NCOPY 32
#define CBLK 256

__device__ inline bf16_8 bzero8() {
    bf16_8 z;
#pragma unroll
    for (int i = 0; i < 8; ++i) z[i] = (__bf16)0.f;
    return z;
}

__device__ inline bf16_8 gatherrow(const __bf16* __restrict__ src, int nb, int kh) {
    bf16_8 a = *(const bf16_8*)(src + (size_t)(nb < 0 ? 0 : nb) * 32 + kh * 8);
    if (nb < 0) a = bzero8();
    return a;
}

// ---- stage 1: count valid child slots per chunk ----
__global__ __launch_bounds__(256) void k_cnt(const int* __restrict__ child, int m8,
                                             int* __restrict__ blockCnt) {
    __shared__ int ws[4];
    const int b = blockIdx.x, tid = threadIdx.x;
    const int chunk = (m8 + CBLK - 1) / CBLK;
    const int s0 = b * chunk, s1 = min(s0 + chunk, m8);
    int c = 0;
    for (int s = s0 + tid; s < s1; s += 256) c += (child[s] >= 0);
#pragma unroll
    for (int d = 1; d < 64; d <<= 1) c += __shfl_xor(c, d);
    if ((tid & 63) == 0) ws[tid >> 6] = c;
    __syncthreads();
    if (tid == 0) blockCnt[b] = ws[0] + ws[1] + ws[2] + ws[3];
}

// ---- stage 2: order-preserving compaction -> perm, invperm ----
__global__ __launch_bounds__(256) void k_compact(const int* __restrict__ child, int m8,
                                                 const int* __restrict__ blockCnt,
                                                 int* __restrict__ perm,
                                                 int* __restrict__ invperm) {
    __shared__ int woff[4];
    __shared__ int sbase;
    const int b = blockIdx.x, tid = threadIdx.x;
    const int chunk = (m8 + CBLK - 1) / CBLK;
    const int s0 = b * chunk, s1 = min(s0 + chunk, m8);
    if (tid == 0) {
        int a = 0;
        for (int i = 0; i < b; ++i) a += blockCnt[i];
        sbase = a;
    }
    __syncthreads();
    int off = sbase;
    for (int base = s0; base < s1; base += 256) {
        const int s = base + tid;
        int c = -1;
        bool v = false;
        if (s < s1) { c = child[s]; v = (c >= 0); }
        unsigned long long m = __ballot(v);
        if ((tid & 63) == 0) woff[tid >> 6] = __popcll(m);
        __syncthreads();
        const int wv = tid >> 6;
        int wpre = 0;
#pragma unroll
        for (int i = 0; i < 4; ++i) if (i < wv) wpre += woff[i];
        const int tot = woff[0] + woff[1] + woff[2] + woff[3];
        const int rank = __popcll(m & ((1ULL << (tid & 63)) - 1ULL));
        if (v) {
            const int pos = off + wpre + rank;
            perm[pos] = c;
            invperm[c] = pos;
        }
        off += tot;
        __syncthreads();
    }
}

// ---- stage 3: re-index rulebooks + permuted features + weights + stats zero ----
__global__ __launch_bounds__(256) void k_reindex(
    const int* __restrict__ nbr, const int* __restrict__ child,
    const int* __restrict__ perm, const int* __restrict__ invperm,
    const float* __restrict__ feats,
    const float* __restrict__ W1, const float* __restrict__ W2a,
    const float* __restrict__ W2b, const float* __restrict__ W3,
    int* __restrict__ nbrP, int* __restrict__ childP, __bf16* __restrict__ fb,
    __bf16* __restrict__ w1t, __bf16* __restrict__ w2at,
    __bf16* __restrict__ w2bt, __bf16* __restrict__ w3t,
    float* __restrict__ statsAll, int n27, int m8, int n32) {
    int t = blockIdx.x * 256 + threadIdx.x;
    if (t < n27) {
        const int p = t / 27, k = t - p * 27;
        const int v = nbr[(size_t)perm[p] * 27 + k];
        nbrP[t] = (v < 0) ? -1 : invperm[v];
        return;
    }
    t -= n27;
    if (t < m8) {
        const int v = child[t];
        childP[t] = (v < 0) ? -1 : invperm[v];
        return;
    }
    t -= m8;
    if (t < n32) {
        const int p = t >> 5, c = t & 31;
        fb[t] = (c < 3) ? (__bf16)feats[(size_t)perm[p] * 3 + c] : (__bf16)0.f;
        return;
    }
    t -= n32;
    if (t < 27648) {
        const int k = t >> 10, r = t & 1023, d = r >> 5, c = r & 31;
        w1t[t] = (c < 3) ? (__bf16)W1[(k * 3 + c) * 32 + d] : (__bf16)0.f;
    } else if (t < 2 * 27648) {
        const int j = t - 27648;
        const int k = j >> 10, r = j & 1023, d = r >> 5, c = r & 31;
        w2at[j] = (__bf16)W2a[(k * 32 + c) * 32 + d];
    } else if (t < 3 * 27648) {
        const int j = t - 2 * 27648;
        const int k = j >> 10, r = j & 1023, d = r >> 5, c = r & 31;
        w2bt[j] = (__bf16)W2b[(k * 32 + c) * 32 + d];
    } else if (t < 3 * 27648 + 8192) {
        const int j = t - 3 * 27648;
        const int k = j >> 10, r = j & 1023, d = r >> 5, c = r & 31;
        w3t[j] = (__bf16)W3[(k * 32 + c) * 32 + d];
    } else if (t < 3 * 27648 + 8192 + 4 * NCOPY * 64) {
        statsAll[t - 3 * 27648 - 8192] = 0.f;
    }
}

// Split-K gathered-GEMM conv (perm space). Block = 4 waves, 32 output sites.
// Wave w: offsets [w*KPW,...), 2 groups of 16 sites. ALL idx then ALL gathers
// issued; sched_barrier(0) forces every gather live (true burst, ~14
// outstanding/wave). fp32 partials -> LDS -> reduce + stats.
template <int KOFF, bool ADD>
__global__ __launch_bounds__(256, 4) void k_conv(
    const __bf16* __restrict__ src,     // [Nsrc,32] bf16
    const int* __restrict__ idx,        // [nout,KOFF] (re-indexed)
    const __bf16* __restrict__ Wt,      // [KOFF][32d][32c] bf16
    const __bf16* __restrict__ addsrc,  // [nout,32] bf16 or null
    __bf16* __restrict__ dst,           // [nout,32] bf16
    float* __restrict__ spart_out,      // [NCOPY][64]
    int nout) {
    constexpr int KPW = (KOFF + 3) / 4;
    __shared__ float part[4][32][34];
    __shared__ float lst[64];

    const int tid = threadIdx.x;
    const int lane = tid & 63;
    const int wv = tid >> 6;
    const int base = blockIdx.x * 32;
    const int sl = lane & 15;   // A row / B col within 16
    const int kh = lane >> 4;   // k-quarter: channels kh*8..kh*8+7
    const int kbeg = wv * KPW;

    if (tid < 64) lst[tid] = 0.f;

    // ---- all idx loads ----
    int nb[2][KPW];
#pragma unroll
    for (int g = 0; g < 2; ++g) {
        const int s = base + g * 16 + sl;
        const bool v = (s < nout);
        const int* ip = idx + (size_t)(v ? s : 0) * KOFF;
#pragma unroll
        for (int j = 0; j < KPW; ++j) {
            const bool kv = (kbeg + j) < KOFF;
            int t = ip[kv ? (kbeg + j) : 0];
            nb[g][j] = (v && kv) ? t : -1;
        }
    }

    // ---- all gathers; barrier forces every load issued & live ----
    bf16_8 av[2][KPW];
#pragma unroll
    for (int j = 0; j < KPW; ++j)
#pragma unroll
        for (int g = 0; g < 2; ++g)
            av[g][j] = gatherrow(src, nb[g][j], kh);
    __builtin_amdgcn_sched_barrier(0);

    // ---- MFMA chain ----
    f32x4 acc[2][2];
#pragma unroll
    for (int g = 0; g < 2; ++g)
#pragma unroll
        for (int h = 0; h < 2; ++h)
#pragma unroll
            for (int r = 0; r < 4; ++r) acc[g][h][r] = 0.f;

#pragma unroll
    for (int j = 0; j < KPW; ++j) {
        int kk = kbeg + j;
        if (kk > KOFF - 1) kk = KOFF - 1;  // av is zero there; value irrelevant
        bf16_8 b0 = *(const bf16_8*)(Wt + kk * 1024 + sl * 32 + kh * 8);
        bf16_8 b1 = *(const bf16_8*)(Wt + kk * 1024 + (16 + sl) * 32 + kh * 8);
        acc[0][0] = __builtin_amdgcn_mfma_f32_16x16x32_bf16(av[0][j], b0, acc[0][0], 0, 0, 0);
        acc[0][1] = __builtin_amdgcn_mfma_f32_16x16x32_bf16(av[0][j], b1, acc[0][1], 0, 0, 0);
        acc[1][0] = __builtin_amdgcn_mfma_f32_16x16x32_bf16(av[1][j], b0, acc[1][0], 0, 0, 0);
        acc[1][1] = __builtin_amdgcn_mfma_f32_16x16x32_bf16(av[1][j], b1, acc[1][1], 0, 0, 0);
    }

    // ---- partials to LDS ----
#pragma unroll
    for (int g = 0; g < 2; ++g)
#pragma unroll
        for (int h = 0; h < 2; ++h)
#pragma unroll
            for (int r = 0; r < 4; ++r)
                part[wv][g * 16 + kh * 4 + r][h * 16 + sl] = acc[g][h][r];
    __syncthreads();

    // ---- reduce + epilogue (threads 0..127: 32 sites x 4 ch-blocks) ----
    if (tid < 128) {
        const int sloc = tid >> 2;
        const int c0 = (tid & 3) * 8;
        float v[8];
#pragma unroll
        for (int i = 0; i < 8; ++i)
            v[i] = part[0][sloc][c0 + i] + part[1][sloc][c0 + i] +
                   part[2][sloc][c0 + i] + part[3][sloc][c0 + i];
        const int site = base + sloc;
        if (site < nout) {
            if (ADD) {
                bf16_8 ad = *(const bf16_8*)(addsrc + (size_t)site * 32 + c0);
#pragma unroll
                for (int i = 0; i < 8; ++i) v[i] += (float)ad[i];
            }
            bf16_8 o;
#pragma unroll
            for (int i = 0; i < 8; ++i) o[i] = (__bf16)v[i];
            *(bf16_8*)(dst + (size_t)site * 32 + c0) = o;
        } else {
#pragma unroll
            for (int i = 0; i < 8; ++i) v[i] = 0.f;
        }
        float sv[8], qv[8];
#pragma unroll
        for (int i = 0; i < 8; ++i) { sv[i] = v[i]; qv[i] = v[i] * v[i]; }
#pragma unroll
        for (int d = 4; d < 64; d <<= 1) {
#pragma unroll
            for (int i = 0; i < 8; ++i) {
                sv[i] += __shfl_xor(sv[i], d);
                qv[i] += __shfl_xor(qv[i], d);
            }
        }
        if ((lane & 60) == 0) {
#pragma unroll
            for (int i = 0; i < 8; ++i) {
                atomicAdd(&lst[c0 + i], sv[i]);
                atomicAdd(&lst[32 + c0 + i], qv[i]);
            }
        }
    }
    __syncthreads();
    if (tid < 64)
        atomicAdd(&spart_out[(blockIdx.x & (NCOPY - 1)) * 64 + tid], lst[tid]);
}

// BN+ReLU apply. Prolog finalizes stats from NCOPY partials. Optional bf16
// out (perm space) and/or fp32 out (scattered to original order via permw).
template <bool WF32, bool WBF>
__global__ __launch_bounds__(256) void k_bn(
    const __bf16* __restrict__ src, const float* __restrict__ spart,
    const float* __restrict__ gamma, const float* __restrict__ beta,
    float inv_cnt, int nrows,
    __bf16* __restrict__ dstb, float* __restrict__ dstf,
    const int* __restrict__ permw) {
    __shared__ float ss[64];
    __shared__ float sc[32], sh[32];
    const int tid = threadIdx.x;
    if (tid < 64) {
        float a = 0.f;
#pragma unroll
        for (int i = 0; i < NCOPY; ++i) a += spart[i * 64 + tid];
        ss[tid] = a;
    }
    __syncthreads();
    if (tid < 32) {
        float mu = ss[tid] * inv_cnt;
        float var = ss[32 + tid] * inv_cnt - mu * mu;
        float s = gamma[tid] * rsqrtf(var + EPSV);
        sc[tid] = s;
        sh[tid] = beta[tid] - mu * s;
    }
    __syncthreads();
    const int gtid = blockIdx.x * blockDim.x + tid;
    const int c0 = (gtid & 3) * 8;
    float scale[8], shift[8];
#pragma unroll
    for (int i = 0; i < 8; ++i) { scale[i] = sc[c0 + i]; shift[i] = sh[c0 + i]; }
    const int rstride = (gridDim.x * blockDim.x) >> 2;
    for (int r = gtid >> 2; r < nrows; r += rstride) {
        const size_t off = (size_t)r * 32 + c0;
        bf16_8 v = *(const bf16_8*)(src + off);
        float y[8];
#pragma unroll
        for (int i = 0; i < 8; ++i) y[i] = fmaxf(fmaf((float)v[i], scale[i], shift[i]), 0.f);
        if (WBF) {
            bf16_8 o;
#pragma unroll
            for (int i = 0; i < 8; ++i) o[i] = (__bf16)y[i];
            *(bf16_8*)(dstb + off) = o;
        }
        if (WF32) {
            f32x4 lo, hi;
#pragma unroll
            for (int i = 0; i < 4; ++i) { lo[i] = y[i]; hi[i] = y[4 + i]; }
            const size_t woff = permw ? ((size_t)permw[r] * 32 + c0) : off;
            *(f32x4*)(dstf + woff) = lo;
            *(f32x4*)(dstf + woff + 4) = hi;
        }
    }
}

extern "C" void kernel_launch(void* const* d_in, const int* in_sizes, int n_in,
                              void* d_out, int out_size, void* d_ws, size_t ws_size,
                              hipStream_t stream) {
    const float* feats = (const float*)d_in[0];
    const int* nbr     = (const int*)d_in[1];
    const int* child   = (const int*)d_in[2];
    const float* W1  = (const float*)d_in[3];
    const float* W2a = (const float*)d_in[4];
    const float* W2b = (const float*)d_in[5];
    const float* W3  = (const float*)d_in[6];
    const float* g1 = (const float*)d_in[7];  const float* b1 = (const float*)d_in[8];
    const float* g2 = (const float*)d_in[9];  const float* b2 = (const float*)d_in[10];
    const float* g3 = (const float*)d_in[11]; const float* b3 = (const float*)d_in[12];
    const float* g4 = (const float*)d_in[13]; const float* b4 = (const float*)d_in[14];

    const int N = in_sizes[0] / 3;   // 131072 active sites
    const int M8 = in_sizes[2];      // child slots (M*8)
    const int M = M8 / 8;            // strided-conv output sites

    float* outp = (float*)d_out;               // [M,32] (original order)
    float* ft2p = outp + (size_t)M * 32;       // [N,32] (original order)

    char* ws = (char*)d_ws;
    float* statsAll = (float*)ws;                         // 4 x NCOPY x 64
    __bf16* w1t  = (__bf16*)(ws + 32768);
    __bf16* w2at = w1t + 27648;
    __bf16* w2bt = w2at + 27648;
    __bf16* w3t  = w2bt + 27648;
    __bf16* X  = (__bf16*)(ws + 215040);                  // perm space
    __bf16* T  = X + (size_t)N * 32;
    __bf16* FB = T + (size_t)N * 32;
    char* p2 = ws + 215040 + 3 * (size_t)N * 64;
    int* perm    = (int*)p2;
    int* invperm = perm + N;
    int* nbrP    = invperm + N;
    int* childP  = nbrP + (size_t)N * 27;
    int* blockCnt = childP + M8;

    float* s1 = statsAll;
    float* s2 = statsAll + NCOPY * 64;
    float* s3 = statsAll + 2 * NCOPY * 64;
    float* s4 = statsAll + 3 * NCOPY * 64;

    // spatial permutation from child slot order
    k_cnt<<<CBLK, 256, 0, stream>>>(child, M8, blockCnt);
    k_compact<<<CBLK, 256, 0, stream>>>(child, M8, blockCnt, perm, invperm);

    const int n27 = N * 27, n32 = N * 32;
    const int rtot = n27 + M8 + n32 + 3 * 27648 + 8192 + 4 * NCOPY * 64;
    k_reindex<<<(rtot + 255) / 256, 256, 0, stream>>>(
        nbr, child, perm, invperm, feats, W1, W2a, W2b, W3,
        nbrP, childP, FB, w1t, w2at, w2bt, w3t, statsAll, n27, M8, n32);

    const int cgrid = (N + 31) / 32;
    const int cgrid3 = (M + 31) / 32;
    const float invN = 1.f / N, invM = 1.f / M;

    // x1 = conv1(featsb)                          FB -> X, s1
    k_conv<27, false><<<cgrid, 256, 0, stream>>>(FB, nbrP, w1t, nullptr, X, s1, N);
    // t1 = bnrelu1(x1)                            X -> T
    k_bn<false, true><<<1024, 256, 0, stream>>>(X, s1, g1, b1, invN, N, T, nullptr, nullptr);
    // br1 = conv2a(t1)                            T -> FB, s2
    k_conv<27, false><<<cgrid, 256, 0, stream>>>(T, nbrP, w2at, nullptr, FB, s2, N);
    // t2 = bnrelu2(br1)                           FB -> T
    k_bn<false, true><<<1024, 256, 0, stream>>>(FB, s2, g2, b2, invN, N, T, nullptr, nullptr);
    // s = x1 + conv2b(t2)                         T (+X) -> FB, s3
    k_conv<27, true><<<cgrid, 256, 0, stream>>>(T, nbrP, w2bt, X, FB, s3, N);
    // ft2 = bnrelu3(s)                            FB -> T (bf16) + ft2p (fp32, perm scatter)
    k_bn<true, true><<<1024, 256, 0, stream>>>(FB, s3, g3, b3, invN, N, T, ft2p, perm);
    // x3 = conv3(ft2)                             T -> X (M rows), s4
    k_conv<8, false><<<cgrid3, 256, 0, stream>>>(T, childP, w3t, nullptr, X, s4, M);
    // out = bnrelu4(x3)                           X -> outp (fp32, original m order)
    k_bn<true, false><<<1024, 256, 0, stream>>>(X, s4, g4, b4, invM, M, nullptr, outp, nullptr);
}

// Round 8
// 181.234 us; speedup vs baseline: 1.0694x; 1.0694x over previous
//
#include <hip/hip_runtime.h>
#include <hip/hip_bf16.h>

// Sparse encoder layer: 3x submanifold conv (27-pt) + strided conv (8-pt),
// 4x training-mode BN+ReLU. bf16 MFMA (fp32 accum) for all convs.
//
// R7 finding: the nb<0 select on the LOADED value forced load->waitcnt->cndmask
// serialization in every previous round (VGPR 56, ~5 outstanding). R8: zero-row
// trick -- feature buffers have a zeroed row N; reindex maps -1 -> N; rulebook
// transposed to k-major [KPAD][npad] with padded entries = N. The gather loop is
// now branch/select-free unconditional loads -> compiler can keep all 14 in
// flight. Keep perm-space spatial indexing (L2 locality) and split-K block.
//
// ws layout (bytes):
//   [0, 32768)      : stats partials, 4 stages x NCOPY(32) x 64 floats
//   [32768, 221184) : w1t/w2at/w2bt bf16 [28][32][32] (k=27 zero) + w3t [8][32][32]
//   [221184, +3x(N+1)*64) : X, T, FB bf16 [N+1,32], row N = 0 (perm space)
//   then: perm[N], invperm[N], nbrT[28][N], childT[8][MP], blockCnt[256]

typedef __bf16 bf16_8 __attribute__((ext_vector_type(8)));
typedef float  f32x4  __attribute__((ext_vector_type(4)));

#define EPSV 1e-5f
#define NCOPY 32
#define CBLK 256

// ---- stage 1: count valid child slots per chunk ----
__global__ __launch_bounds__(256) void k_cnt(const int* __restrict__ child, int m8,
                                             int* __restrict__ blockCnt) {
    __shared__ int ws[4];
    const int b = blockIdx.x, tid = threadIdx.x;
    const int chunk = (m8 + CBLK - 1) / CBLK;
    const int s0 = b * chunk, s1 = min(s0 + chunk, m8);
    int c = 0;
    for (int s = s0 + tid; s < s1; s += 256) c += (child[s] >= 0);
#pragma unroll
    for (int d = 1; d < 64; d <<= 1) c += __shfl_xor(c, d);
    if ((tid & 63) == 0) ws[tid >> 6] = c;
    __syncthreads();
    if (tid == 0) blockCnt[b] = ws[0] + ws[1] + ws[2] + ws[3];
}

// ---- stage 2: order-preserving compaction -> perm, invperm ----
__global__ __launch_bounds__(256) void k_compact(const int* __restrict__ child, int m8,
                                                 const int* __restrict__ blockCnt,
                                                 int* __restrict__ perm,
                                                 int* __restrict__ invperm) {
    __shared__ int woff[4];
    __shared__ int sbase;
    const int b = blockIdx.x, tid = threadIdx.x;
    const int chunk = (m8 + CBLK - 1) / CBLK;
    const int s0 = b * chunk, s1 = min(s0 + chunk, m8);
    if (tid == 0) {
        int a = 0;
        for (int i = 0; i < b; ++i) a += blockCnt[i];
        sbase = a;
    }
    __syncthreads();
    int off = sbase;
    for (int base = s0; base < s1; base += 256) {
        const int s = base + tid;
        int c = -1;
        bool v = false;
        if (s < s1) { c = child[s]; v = (c >= 0); }
        unsigned long long m = __ballot(v);
        if ((tid & 63) == 0) woff[tid >> 6] = __popcll(m);
        __syncthreads();
        const int wv = tid >> 6;
        int wpre = 0;
#pragma unroll
        for (int i = 0; i < 4; ++i) if (i < wv) wpre += woff[i];
        const int tot = woff[0] + woff[1] + woff[2] + woff[3];
        const int rank = __popcll(m & ((1ULL << (tid & 63)) - 1ULL));
        if (v) {
            const int pos = off + wpre + rank;
            perm[pos] = c;
            invperm[c] = pos;
        }
        off += tot;
        __syncthreads();
    }
}

// ---- stage 3: k-major rulebooks (ZR-padded) + permuted features + weights ----
__global__ __launch_bounds__(256) void k_reindex(
    const int* __restrict__ nbr, const int* __restrict__ child,
    const int* __restrict__ perm, const int* __restrict__ invperm,
    const float* __restrict__ feats,
    const float* __restrict__ W1, const float* __restrict__ W2a,
    const float* __restrict__ W2b, const float* __restrict__ W3,
    int* __restrict__ nbrT, int* __restrict__ childT,
    __bf16* __restrict__ X, __bf16* __restrict__ T, __bf16* __restrict__ FB,
    __bf16* __restrict__ w1t, __bf16* __restrict__ w2at,
    __bf16* __restrict__ w2bt, __bf16* __restrict__ w3t,
    float* __restrict__ statsAll,
    int N, int M, int MP) {
    int t = blockIdx.x * 256 + threadIdx.x;
    // nbrT [28][N], entries with k==27 -> ZR(=N)
    if (t < 28 * N) {
        const int k = t / N, p = t - k * N;
        int o = N;
        if (k < 27) {
            const int v = nbr[(size_t)perm[p] * 27 + k];
            o = (v < 0) ? N : invperm[v];
        }
        nbrT[t] = o;
        return;
    }
    t -= 28 * N;
    // childT [8][MP], m >= M -> ZR
    if (t < 8 * MP) {
        const int k = t / MP, m = t - k * MP;
        int o = N;
        if (m < M) {
            const int v = child[(size_t)m * 8 + k];
            o = (v < 0) ? N : invperm[v];
        }
        childT[t] = o;
        return;
    }
    t -= 8 * MP;
    // permuted features -> FB rows <N
    if (t < N * 32) {
        const int p = t >> 5, c = t & 31;
        FB[t] = (c < 3) ? (__bf16)feats[(size_t)perm[p] * 3 + c] : (__bf16)0.f;
        return;
    }
    t -= N * 32;
    // zero row N of X, T, FB
    if (t < 96) {
        const int b = t >> 5, c = t & 31;
        __bf16* p = (b == 0) ? X : (b == 1) ? T : FB;
        p[(size_t)N * 32 + c] = (__bf16)0.f;
        return;
    }
    t -= 96;
    // weights: [28][32d][32c] (k=27 zero) x3, w3t [8][32][32]
    if (t < 28672) {
        const int k = t >> 10, r = t & 1023, d = r >> 5, c = r & 31;
        w1t[t] = (k < 27 && c < 3) ? (__bf16)W1[(k * 3 + c) * 32 + d] : (__bf16)0.f;
        return;
    }
    t -= 28672;
    if (t < 28672) {
        const int k = t >> 10, r = t & 1023, d = r >> 5, c = r & 31;
        w2at[t] = (k < 27) ? (__bf16)W2a[(k * 32 + c) * 32 + d] : (__bf16)0.f;
        return;
    }
    t -= 28672;
    if (t < 28672) {
        const int k = t >> 10, r = t & 1023, d = r >> 5, c = r & 31;
        w2bt[t] = (k < 27) ? (__bf16)W2b[(k * 32 + c) * 32 + d] : (__bf16)0.f;
        return;
    }
    t -= 28672;
    if (t < 8192) {
        const int k = t >> 10, r = t & 1023, d = r >> 5, c = r & 31;
        w3t[t] = (__bf16)W3[(k * 32 + c) * 32 + d];
        return;
    }
    t -= 8192;
    if (t < 4 * NCOPY * 64) statsAll[t] = 0.f;
}

// Split-K gathered-GEMM conv (perm space, zero-row masked). Block = 4 waves,
// 32 output sites. Wave w: KPW offsets, 2 groups of 16 sites. Idx loads are
// coalesced (k-major table); gathers are unconditional (ZR rows are zero).
// fp32 partials -> LDS -> reduce + stats.
template <int KOFF, bool ADD>
__global__ __launch_bounds__(256, 4) void k_conv(
    const __bf16* __restrict__ src,     // [npadrows+1,32] bf16, row ZR = 0
    const int* __restrict__ idxT,       // [KPAD][npad] site-major per k
    const __bf16* __restrict__ Wt,      // [KPAD][32d][32c] bf16
    const __bf16* __restrict__ addsrc,  // [nout,32] bf16 or null
    __bf16* __restrict__ dst,           // [nout,32] bf16
    float* __restrict__ spart_out,      // [NCOPY][64]
    int nout, int npad) {
    constexpr int KPAD = ((KOFF + 3) / 4) * 4;
    constexpr int KPW = KPAD / 4;
    __shared__ float part[4][32][34];
    __shared__ float lst[64];

    const int tid = threadIdx.x;
    const int lane = tid & 63;
    const int wv = tid >> 6;
    const int base = blockIdx.x * 32;
    const int sl = lane & 15;   // A row / B col within 16
    const int kh = lane >> 4;   // k-quarter: channels kh*8..kh*8+7
    const int kbeg = wv * KPW;

    if (tid < 64) lst[tid] = 0.f;

    // ---- idx loads: coalesced, unconditional ----
    int nb[2][KPW];
#pragma unroll
    for (int j = 0; j < KPW; ++j)
#pragma unroll
        for (int g = 0; g < 2; ++g)
            nb[g][j] = idxT[(kbeg + j) * npad + base + g * 16 + sl];

    // ---- gathers: unconditional loads, no selects -> true burst ----
    bf16_8 av[2][KPW];
#pragma unroll
    for (int j = 0; j < KPW; ++j)
#pragma unroll
        for (int g = 0; g < 2; ++g)
            av[g][j] = *(const bf16_8*)(src + (size_t)nb[g][j] * 32 + kh * 8);
    __builtin_amdgcn_sched_barrier(0);

    // ---- MFMA chain ----
    f32x4 acc[2][2];
#pragma unroll
    for (int g = 0; g < 2; ++g)
#pragma unroll
        for (int h = 0; h < 2; ++h)
#pragma unroll
            for (int r = 0; r < 4; ++r) acc[g][h][r] = 0.f;

#pragma unroll
    for (int j = 0; j < KPW; ++j) {
        const int kk = kbeg + j;
        bf16_8 b0 = *(const bf16_8*)(Wt + kk * 1024 + sl * 32 + kh * 8);
        bf16_8 b1 = *(const bf16_8*)(Wt + kk * 1024 + (16 + sl) * 32 + kh * 8);
        acc[0][0] = __builtin_amdgcn_mfma_f32_16x16x32_bf16(av[0][j], b0, acc[0][0], 0, 0, 0);
        acc[0][1] = __builtin_amdgcn_mfma_f32_16x16x32_bf16(av[0][j], b1, acc[0][1], 0, 0, 0);
        acc[1][0] = __builtin_amdgcn_mfma_f32_16x16x32_bf16(av[1][j], b0, acc[1][0], 0, 0, 0);
        acc[1][1] = __builtin_amdgcn_mfma_f32_16x16x32_bf16(av[1][j], b1, acc[1][1], 0, 0, 0);
    }

    // ---- partials to LDS ----
#pragma unroll
    for (int g = 0; g < 2; ++g)
#pragma unroll
        for (int h = 0; h < 2; ++h)
#pragma unroll
            for (int r = 0; r < 4; ++r)
                part[wv][g * 16 + kh * 4 + r][h * 16 + sl] = acc[g][h][r];
    __syncthreads();

    // ---- reduce + epilogue (threads 0..127: 32 sites x 4 ch-blocks) ----
    if (tid < 128) {
        const int sloc = tid >> 2;
        const int c0 = (tid & 3) * 8;
        float v[8];
#pragma unroll
        for (int i = 0; i < 8; ++i)
            v[i] = part[0][sloc][c0 + i] + part[1][sloc][c0 + i] +
                   part[2][sloc][c0 + i] + part[3][sloc][c0 + i];
        const int site = base + sloc;
        if (site < nout) {
            if (ADD) {
                bf16_8 ad = *(const bf16_8*)(addsrc + (size_t)site * 32 + c0);
#pragma unroll
                for (int i = 0; i < 8; ++i) v[i] += (float)ad[i];
            }
            bf16_8 o;
#pragma unroll
            for (int i = 0; i < 8; ++i) o[i] = (__bf16)v[i];
            *(bf16_8*)(dst + (size_t)site * 32 + c0) = o;
        } else {
#pragma unroll
            for (int i = 0; i < 8; ++i) v[i] = 0.f;
        }
        float sv[8], qv[8];
#pragma unroll
        for (int i = 0; i < 8; ++i) { sv[i] = v[i]; qv[i] = v[i] * v[i]; }
#pragma unroll
        for (int d = 4; d < 64; d <<= 1) {
#pragma unroll
            for (int i = 0; i < 8; ++i) {
                sv[i] += __shfl_xor(sv[i], d);
                qv[i] += __shfl_xor(qv[i], d);
            }
        }
        if ((lane & 60) == 0) {
#pragma unroll
            for (int i = 0; i < 8; ++i) {
                atomicAdd(&lst[c0 + i], sv[i]);
                atomicAdd(&lst[32 + c0 + i], qv[i]);
            }
        }
    }
    __syncthreads();
    if (tid < 64)
        atomicAdd(&spart_out[(blockIdx.x & (NCOPY - 1)) * 64 + tid], lst[tid]);
}

// BN+ReLU apply. Prolog finalizes stats from NCOPY partials. Optional bf16
// out (perm space) and/or fp32 out (scattered to original order via permw).
template <bool WF32, bool WBF>
__global__ __launch_bounds__(256) void k_bn(
    const __bf16* __restrict__ src, const float* __restrict__ spart,
    const float* __restrict__ gamma, const float* __restrict__ beta,
    float inv_cnt, int nrows,
    __bf16* __restrict__ dstb, float* __restrict__ dstf,
    const int* __restrict__ permw) {
    __shared__ float ss[64];
    __shared__ float sc[32], sh[32];
    const int tid = threadIdx.x;
    if (tid < 64) {
        float a = 0.f;
#pragma unroll
        for (int i = 0; i < NCOPY; ++i) a += spart[i * 64 + tid];
        ss[tid] = a;
    }
    __syncthreads();
    if (tid < 32) {
        float mu = ss[tid] * inv_cnt;
        float var = ss[32 + tid] * inv_cnt - mu * mu;
        float s = gamma[tid] * rsqrtf(var + EPSV);
        sc[tid] = s;
        sh[tid] = beta[tid] - mu * s;
    }
    __syncthreads();
    const int gtid = blockIdx.x * blockDim.x + tid;
    const int c0 = (gtid & 3) * 8;
    float scale[8], shift[8];
#pragma unroll
    for (int i = 0; i < 8; ++i) { scale[i] = sc[c0 + i]; shift[i] = sh[c0 + i]; }
    const int rstride = (gridDim.x * blockDim.x) >> 2;
    for (int r = gtid >> 2; r < nrows; r += rstride) {
        const size_t off = (size_t)r * 32 + c0;
        bf16_8 v = *(const bf16_8*)(src + off);
        float y[8];
#pragma unroll
        for (int i = 0; i < 8; ++i) y[i] = fmaxf(fmaf((float)v[i], scale[i], shift[i]), 0.f);
        if (WBF) {
            bf16_8 o;
#pragma unroll
            for (int i = 0; i < 8; ++i) o[i] = (__bf16)y[i];
            *(bf16_8*)(dstb + off) = o;
        }
        if (WF32) {
            f32x4 lo, hi;
#pragma unroll
            for (int i = 0; i < 4; ++i) { lo[i] = y[i]; hi[i] = y[4 + i]; }
            const size_t woff = permw ? ((size_t)permw[r] * 32 + c0) : off;
            *(f32x4*)(dstf + woff) = lo;
            *(f32x4*)(dstf + woff + 4) = hi;
        }
    }
}

extern "C" void kernel_launch(void* const* d_in, const int* in_sizes, int n_in,
                              void* d_out, int out_size, void* d_ws, size_t ws_size,
                              hipStream_t stream) {
    const float* feats = (const float*)d_in[0];
    const int* nbr     = (const int*)d_in[1];
    const int* child   = (const int*)d_in[2];
    const float* W1  = (const float*)d_in[3];
    const float* W2a = (const float*)d_in[4];
    const float* W2b = (const float*)d_in[5];
    const float* W3  = (const float*)d_in[6];
    const float* g1 = (const float*)d_in[7];  const float* b1 = (const float*)d_in[8];
    const float* g2 = (const float*)d_in[9];  const float* b2 = (const float*)d_in[10];
    const float* g3 = (const float*)d_in[11]; const float* b3 = (const float*)d_in[12];
    const float* g4 = (const float*)d_in[13]; const float* b4 = (const float*)d_in[14];

    const int N = in_sizes[0] / 3;        // 131072 active sites (mult of 32)
    const int M8 = in_sizes[2];           // child slots (M*8)
    const int M = M8 / 8;                 // strided-conv output sites
    const int MP = ((M + 31) / 32) * 32;  // padded site count for childT

    float* outp = (float*)d_out;               // [M,32] (original order)
    float* ft2p = outp + (size_t)M * 32;       // [N,32] (original order)

    char* ws = (char*)d_ws;
    float* statsAll = (float*)ws;                         // 4 x NCOPY x 64
    __bf16* w1t  = (__bf16*)(ws + 32768);                 // [28][32][32]
    __bf16* w2at = w1t + 28672;
    __bf16* w2bt = w2at + 28672;
    __bf16* w3t  = w2bt + 28672;                          // [8][32][32]
    __bf16* X  = (__bf16*)(ws + 221184);                  // [N+1,32] perm space
    __bf16* T  = X + (size_t)(N + 1) * 32;
    __bf16* FB = T + (size_t)(N + 1) * 32;
    char* p2 = (char*)(FB + (size_t)(N + 1) * 32);
    int* perm    = (int*)p2;
    int* invperm = perm + N;
    int* nbrT    = invperm + N;                           // [28][N]
    int* childT  = nbrT + (size_t)28 * N;                 // [8][MP]
    int* blockCnt = childT + (size_t)8 * MP;

    float* s1 = statsAll;
    float* s2 = statsAll + NCOPY * 64;
    float* s3 = statsAll + 2 * NCOPY * 64;
    float* s4 = statsAll + 3 * NCOPY * 64;

    // spatial permutation from child slot order
    k_cnt<<<CBLK, 256, 0, stream>>>(child, M8, blockCnt);
    k_compact<<<CBLK, 256, 0, stream>>>(child, M8, blockCnt, perm, invperm);

    const int rtot = 28 * N + 8 * MP + N * 32 + 96 + 3 * 28672 + 8192 + 4 * NCOPY * 64;
    k_reindex<<<(rtot + 255) / 256, 256, 0, stream>>>(
        nbr, child, perm, invperm, feats, W1, W2a, W2b, W3,
        nbrT, childT, X, T, FB, w1t, w2at, w2bt, w3t, statsAll, N, M, MP);

    const int cgrid = N / 32;
    const int cgrid3 = MP / 32;
    const float invN = 1.f / N, invM = 1.f / M;

    // x1 = conv1(featsb)                          FB -> X, s1
    k_conv<27, false><<<cgrid, 256, 0, stream>>>(FB, nbrT, w1t, nullptr, X, s1, N, N);
    // t1 = bnrelu1(x1)                            X -> T
    k_bn<false, true><<<1024, 256, 0, stream>>>(X, s1, g1, b1, invN, N, T, nullptr, nullptr);
    // br1 = conv2a(t1)                            T -> FB, s2
    k_conv<27, false><<<cgrid, 256, 0, stream>>>(T, nbrT, w2at, nullptr, FB, s2, N, N);
    // t2 = bnrelu2(br1)                           FB -> T
    k_bn<false, true><<<1024, 256, 0, stream>>>(FB, s2, g2, b2, invN, N, T, nullptr, nullptr);
    // s = x1 + conv2b(t2)                         T (+X) -> FB, s3
    k_conv<27, true><<<cgrid, 256, 0, stream>>>(T, nbrT, w2bt, X, FB, s3, N, N);
    // ft2 = bnrelu3(s)                            FB -> T (bf16) + ft2p (fp32, perm scatter)
    k_bn<true, true><<<1024, 256, 0, stream>>>(FB, s3, g3, b3, invN, N, T, ft2p, perm);
    // x3 = conv3(ft2)                             T -> X (M rows), s4
    k_conv<8, false><<<cgrid3, 256, 0, stream>>>(T, childT, w3t, nullptr, X, s4, M, MP);
    // out = bnrelu4(x3)                           X -> outp (fp32, original m order)
    k_bn<true, false><<<1024, 256, 0, stream>>>(X, s4, g4, b4, invM, M, nullptr, outp, nullptr);
}